// Round 11
// baseline (94.891 us; speedup 1.0000x reference)
//
#include <hip/hip_runtime.h>
#include <hip/hip_bf16.h>

#define SROWS 16384
#define DIMK  4096
#define NE    64
#define BM    16                // rows per block
#define NBLK  (SROWS/BM)        // 1024 blocks = 4/CU
#define KSEG  1024              // k-range per wave (4-way k-split)
#define NSTEP 16                // steps; per step each wave consumes 64 k
#define WSPLIT_SHORTS 262144    // shorts per (hi|lo) plane of pre-split W
#define WSOFF_F 262144          // f32 offset of partials region (skip 1 MB W-split)
#define WSOFF2  (WSOFF_F + NBLK*64)

typedef __attribute__((ext_vector_type(8))) short short8;
typedef __attribute__((ext_vector_type(4))) float f32x4;

// split 8 f32 -> 8 hi bf16 + 8 lo bf16 via HW cvt (RNE); f ~= hi + lo
__device__ __forceinline__ void split8(const float4 a, const float4 c, short8& hi, short8& lo) {
    float f[8] = {a.x, a.y, a.z, a.w, c.x, c.y, c.z, c.w};
    #pragma unroll
    for (int i = 0; i < 8; ++i) {
        unsigned short h = __bfloat16_as_ushort(__float2bfloat16(f[i]));
        float hf = __uint_as_float((unsigned)h << 16);
        unsigned short l = __bfloat16_as_ushort(__float2bfloat16(f[i] - hf));
        hi[i] = (short)h;
        lo[i] = (short)l;
    }
}

// pre-pass: split W into bf16 hi/lo planes in B-fragment order [k/8][e][8]
__global__ void w_split(const float* __restrict__ W, unsigned short* __restrict__ wsp)
{
    const int idx   = blockIdx.x * 256 + threadIdx.x;   // 0..32767
    const int kslot = idx & 511;
    const int e     = idx >> 9;
    const float* p = W + (size_t)e * DIMK + kslot * 8;
    float4 va = *reinterpret_cast<const float4*>(p);
    float4 vb = *reinterpret_cast<const float4*>(p + 4);
    short8 hi, lo;
    split8(va, vb, hi, lo);
    *reinterpret_cast<short8*>(wsp + (size_t)(kslot * 64 + e) * 8)                 = hi;
    *reinterpret_cast<short8*>(wsp + WSPLIT_SHORTS + (size_t)(kslot * 64 + e) * 8) = lo;
}

__global__ __launch_bounds__(256, 4) void gate_main(
    const float* __restrict__ x, const unsigned short* __restrict__ wsp,
    const float* __restrict__ b, float* __restrict__ out, float* __restrict__ ws)
{
    __shared__ float smem[4672];       // epilogue only: part[3072] | Lb[64*17] | red[512]
    float* const part = smem;
    float* const Lb   = smem + 3072;
    float* const red  = smem + 4160;

    const int tid  = threadIdx.x;
    const int lane = tid & 63;
    const int ksw  = __builtin_amdgcn_readfirstlane(tid >> 6);  // 0..3 (k-split)
    const int row0 = blockIdx.x * BM;

    // A: lane's private fragment stream (row = lane&15, k-slice = (lane>>4)*8)
    const float* xA = x + (size_t)(row0 + (lane & 15)) * DIMK
                        + ksw * KSEG + (lane >> 4) * 8;
    const unsigned short* wBbase = wsp + ((size_t)(ksw * 128) * 64) * 8;

    f32x4 acc[4];
    #pragma unroll
    for (int n = 0; n < 4; ++n) acc[n] = (f32x4){0.f, 0.f, 0.f, 0.f};

    // ---- prologue: step 0's x fragments in regs ----
    float4 a00 = *reinterpret_cast<const float4*>(xA);
    float4 a01 = *reinterpret_cast<const float4*>(xA + 4);
    float4 a10 = *reinterpret_cast<const float4*>(xA + 32);
    float4 a11 = *reinterpret_cast<const float4*>(xA + 36);

    #pragma unroll 1
    for (int st = 0; st < NSTEP; ++st) {
        // issue next step's x loads (clamped tail; redundant reload harmless)
        const int pst = (st + 1 < NSTEP) ? st + 1 : NSTEP - 1;
        const float* xp = xA + (size_t)pst * 64;
        float4 p00 = *reinterpret_cast<const float4*>(xp);
        float4 p01 = *reinterpret_cast<const float4*>(xp + 4);
        float4 p10 = *reinterpret_cast<const float4*>(xp + 32);
        float4 p11 = *reinterpret_cast<const float4*>(xp + 36);
        __builtin_amdgcn_sched_barrier(0);   // pin: prefetch issued before compute

        #pragma unroll
        for (int c2 = 0; c2 < 2; ++c2) {
            short8 ah, al;
            if (c2 == 0) split8(a00, a01, ah, al);
            else         split8(a10, a11, ah, al);

            // B fragments direct from L2-resident pre-split W
            const int ksl = st * 8 + c2 * 4 + (lane >> 4);          // 0..127
            const unsigned short* bp = wBbase + ((size_t)ksl * 64 + (lane & 15)) * 8;
            short8 bh[4], bl[4];
            #pragma unroll
            for (int n = 0; n < 4; ++n) {
                bh[n] = *reinterpret_cast<const short8*>(bp + n * 128);
                bl[n] = *reinterpret_cast<const short8*>(bp + WSPLIT_SHORTS + n * 128);
            }

            #pragma unroll
            for (int n = 0; n < 4; ++n)
                acc[n] = __builtin_amdgcn_mfma_f32_16x16x32_bf16(ah, bh[n], acc[n], 0, 0, 0);
            #pragma unroll
            for (int n = 0; n < 4; ++n)
                acc[n] = __builtin_amdgcn_mfma_f32_16x16x32_bf16(ah, bl[n], acc[n], 0, 0, 0);
            #pragma unroll
            for (int n = 0; n < 4; ++n)
                acc[n] = __builtin_amdgcn_mfma_f32_16x16x32_bf16(al, bh[n], acc[n], 0, 0, 0);
        }

        __builtin_amdgcn_sched_barrier(0);   // pin: compute done before rotate
        a00 = p00; a01 = p01; a10 = p10; a11 = p11;
    }

    __syncthreads();

    // ---- 4-way k-reduce via LDS ----
    if (ksw > 0) {
        #pragma unroll
        for (int n = 0; n < 4; ++n)
            #pragma unroll
            for (int j = 0; j < 4; ++j)
                part[(ksw - 1) * 1024 + lane * 16 + n * 4 + j] = acc[n][j];
    }
    __syncthreads();
    if (ksw == 0) {
        #pragma unroll
        for (int n = 0; n < 4; ++n) {
            #pragma unroll
            for (int j = 0; j < 4; ++j) {
                float v = acc[n][j]
                        + part[0 * 1024 + lane * 16 + n * 4 + j]
                        + part[1 * 1024 + lane * 16 + n * 4 + j]
                        + part[2 * 1024 + lane * 16 + n * 4 + j];
                // C layout (m89-verified): col = lane&15, row = (lane>>4)*4 + j
                const int e  = n * 16 + (lane & 15);
                const int rl = (lane >> 4) * 4 + j;
                Lb[e * 17 + rl] = v;
            }
        }
    }
    __syncthreads();

    // ---- softmax + top-2 per row (lane = expert), 4 rows/wave ----
    float impAcc = 0.f, cntAcc = 0.f;
    const float blane = b[lane];
    float* outIdx = out;
    float* outVal = out + (size_t)SROWS * 2;

    #pragma unroll 1
    for (int rr = 0; rr < 4; ++rr) {
        const int r = ksw * 4 + rr;
        const float logit = Lb[lane * 17 + r] + blane;

        float v1 = logit; int i1 = lane;
        #pragma unroll
        for (int off = 32; off; off >>= 1) {
            float ov = __shfl_xor(v1, off);
            int   oi = __shfl_xor(i1, off);
            if (ov > v1 || (ov == v1 && oi < i1)) { v1 = ov; i1 = oi; }
        }
        float p = expf(logit - v1);
        float ssum = p;
        #pragma unroll
        for (int off = 32; off; off >>= 1) ssum += __shfl_xor(ssum, off);

        float v2 = (lane == i1) ? -3.402823466e38f : logit;
        int i2 = lane;
        #pragma unroll
        for (int off = 32; off; off >>= 1) {
            float ov = __shfl_xor(v2, off);
            int   oi = __shfl_xor(i2, off);
            if (ov > v2 || (ov == v2 && oi < i2)) { v2 = ov; i2 = oi; }
        }

        impAcc += p / ssum;
        cntAcc += (i1 == lane) ? 1.f : 0.f;

        if (lane == 0) {
            const int sr = row0 + r;
            outIdx[sr * 2 + 0] = (float)i1;
            outIdx[sr * 2 + 1] = (float)i2;
            outVal[sr * 2 + 0] = 1.f / ssum;
            outVal[sr * 2 + 1] = expf(v2 - v1) / ssum;
        }
    }

    // ---- per-block reduce of importance / count partials ----
    __syncthreads();
    red[ksw * 64 + lane]       = impAcc;
    red[256 + ksw * 64 + lane] = cntAcc;
    __syncthreads();
    if (tid < 64) {
        float si = 0.f, sc2 = 0.f;
        #pragma unroll
        for (int g = 0; g < 4; ++g) {
            si  += red[g * 64 + tid];
            sc2 += red[256 + g * 64 + tid];
        }
        ws[WSOFF_F + (size_t)blockIdx.x * 64 + tid] = si;
        ws[WSOFF2  + (size_t)blockIdx.x * 64 + tid] = sc2;
    }
}

__global__ void gate_reduce(const float* __restrict__ ws, float* __restrict__ out)
{
    __shared__ float li[64 * 64], lc[64 * 64];     // [group][expert]
    const int t = threadIdx.x;                     // 1024 threads
    const int g  = t >> 4;                         // 0..63, 16 blocks each
    const int e4 = (t & 15) * 4;                   // expert quad
    float4 si = make_float4(0.f, 0.f, 0.f, 0.f);
    float4 sc = make_float4(0.f, 0.f, 0.f, 0.f);
    const int base = g * 16;
    #pragma unroll 4
    for (int bb = base; bb < base + 16; ++bb) {
        float4 a = *reinterpret_cast<const float4*>(&ws[WSOFF_F + (size_t)bb * 64 + e4]);
        float4 c = *reinterpret_cast<const float4*>(&ws[WSOFF2  + (size_t)bb * 64 + e4]);
        si.x += a.x; si.y += a.y; si.z += a.z; si.w += a.w;
        sc.x += c.x; sc.y += c.y; sc.z += c.z; sc.w += c.w;
    }
    *reinterpret_cast<float4*>(&li[g * 64 + e4]) = si;
    *reinterpret_cast<float4*>(&lc[g * 64 + e4]) = sc;
    __syncthreads();
    if (t < 64) {
        float ti = 0.f, tc = 0.f;
        #pragma unroll 8
        for (int gg = 0; gg < 64; ++gg) { ti += li[gg * 64 + t]; tc += lc[gg * 64 + t]; }
        li[t] = ti * tc;    // reuse row 0
    }
    __syncthreads();
    if (t == 0) {
        float s = 0.f;
        for (int i = 0; i < NE; ++i) s += li[i];
        out[(size_t)SROWS * 4] = s * ((float)NE / ((float)SROWS * (float)SROWS));
    }
}

extern "C" void kernel_launch(void* const* d_in, const int* in_sizes, int n_in,
                              void* d_out, int out_size, void* d_ws, size_t ws_size,
                              hipStream_t stream)
{
    const float* x = (const float*)d_in[0];
    const float* W = (const float*)d_in[1];
    const float* b = (const float*)d_in[2];
    float* out = (float*)d_out;
    unsigned short* wsp = (unsigned short*)d_ws;
    float* wsf = (float*)d_ws;

    w_split<<<128, 256, 0, stream>>>(W, wsp);
    gate_main<<<NBLK, 256, 0, stream>>>(x, wsp, b, out, wsf);
    gate_reduce<<<1, 1024, 0, stream>>>(wsf, out);
}

// Round 12
// 85.076 us; speedup vs baseline: 1.1154x; 1.1154x over previous
//
#include <hip/hip_runtime.h>
#include <hip/hip_bf16.h>

#define SROWS 16384
#define DIMK  4096
#define NE    64
#define BM    16                // rows per block
#define NBLK  (SROWS/BM)        // 1024 blocks = 4/CU
#define KSEG  1024              // k-range per wave (4-way k-split)
#define NSTEP 16                // steps; per step each wave consumes 64 k
#define SBK   64
#define WSPLIT_SHORTS 262144    // shorts per (hi|lo) plane of pre-split W
#define WSOFF_F 262144          // f32 offset of partials region (skip 1 MB W-split)
#define WSOFF2  (WSOFF_F + NBLK*64)

typedef __attribute__((ext_vector_type(8))) short short8;
typedef __attribute__((ext_vector_type(4))) float f32x4;

// split 8 f32 -> 8 hi bf16 + 8 lo bf16 via HW cvt (RNE); f ~= hi + lo
__device__ __forceinline__ void split8(const float4 a, const float4 c, short8& hi, short8& lo) {
    float f[8] = {a.x, a.y, a.z, a.w, c.x, c.y, c.z, c.w};
    #pragma unroll
    for (int i = 0; i < 8; ++i) {
        unsigned short h = __bfloat16_as_ushort(__float2bfloat16(f[i]));
        float hf = __uint_as_float((unsigned)h << 16);
        unsigned short l = __bfloat16_as_ushort(__float2bfloat16(f[i] - hf));
        hi[i] = (short)h;
        lo[i] = (short)l;
    }
}

// pre-pass: split W into bf16 hi/lo planes in B-fragment order [k/8][e][8]
__global__ void w_split(const float* __restrict__ W, unsigned short* __restrict__ wsp)
{
    const int idx   = blockIdx.x * 256 + threadIdx.x;   // 0..32767
    const int kslot = idx & 511;
    const int e     = idx >> 9;
    const float* p = W + (size_t)e * DIMK + kslot * 8;
    float4 va = *reinterpret_cast<const float4*>(p);
    float4 vb = *reinterpret_cast<const float4*>(p + 4);
    short8 hi, lo;
    split8(va, vb, hi, lo);
    *reinterpret_cast<short8*>(wsp + (size_t)(kslot * 64 + e) * 8)                 = hi;
    *reinterpret_cast<short8*>(wsp + WSPLIT_SHORTS + (size_t)(kslot * 64 + e) * 8) = lo;
}

// async global -> LDS, 16B per lane (DMA; dst = wave-uniform base + lane*16)
__device__ __forceinline__ void gl_lds16(const void* g, void* l) {
    __builtin_amdgcn_global_load_lds(
        (const __attribute__((address_space(1))) void*)g,
        (__attribute__((address_space(3))) void*)l, 16, 0, 0);
}

__global__ __launch_bounds__(256, 4) void gate_main(
    const float* __restrict__ x, const unsigned short* __restrict__ wsp,
    const float* __restrict__ b, float* __restrict__ out, float* __restrict__ ws)
{
    __shared__ __align__(16) char smem[32768];
    // main loop: wave-private slabs: wave ksw at [ksw*8192, +8192): 2 buffers x 4 KB
    //            slab layout [16 rows][16 granules x 16B], src-XOR-swizzled
    // epilogue alias: part[3072 f32] | Lb[64*17 f32] | red[512 f32]

    const int tid  = threadIdx.x;
    const int lane = tid & 63;
    const int ksw  = __builtin_amdgcn_readfirstlane(tid >> 6);  // 0..3 (k-split)
    const int row0 = blockIdx.x * BM;

    // ---- wave-private staging: 4 slots/lane, granule XOR-swizzled ----
    const float* xsq[4];
    #pragma unroll
    for (int q = 0; q < 4; ++q) {
        const int rowq = q * 4 + (lane >> 4);          // (q*64+lane)>>4
        const int gs   = (lane & 15) ^ (rowq & 7);
        xsq[q] = x + (size_t)(row0 + rowq) * DIMK + ksw * KSEG + gs * 4;
    }
    char* const slab = smem + ksw * 8192;

    auto STAGE = [&](int st, int bsel) {
        char* xb = slab + bsel * 4096;
        #pragma unroll
        for (int q = 0; q < 4; ++q)
            gl_lds16(xsq[q] + (size_t)st * SBK, xb + q * 1024 + lane * 16);
    };

    f32x4 acc[4];
    #pragma unroll
    for (int n = 0; n < 4; ++n) acc[n] = (f32x4){0.f, 0.f, 0.f, 0.f};

    const int rm = lane & 7;                       // (row&7) for consume swizzle, row = lane&15
    const char* xrow = slab + (lane & 15) * 256;   // this lane's row within its slab
    const unsigned short* wBbase = wsp + ((size_t)(ksw * 128) * 64) * 8;

    STAGE(0, 0);

    #pragma unroll 1
    for (int st = 0; st < NSTEP; ++st) {
        // wait this wave's own DMA(st) (issued one full step ago); nothing else outstanding
        asm volatile("s_waitcnt vmcnt(0)" ::: "memory");
        __builtin_amdgcn_sched_barrier(0);

        const char* xb = xrow + (st & 1) * 4096;
        const int g0 = 2 * (lane >> 4);

        // x fragments for BOTH phases from LDS (lgkm counter, independent of vmem)
        float4 xa0 = *reinterpret_cast<const float4*>(xb + ((g0    ) ^ rm) * 16);
        float4 xc0 = *reinterpret_cast<const float4*>(xb + ((g0 + 1) ^ rm) * 16);
        float4 xa1 = *reinterpret_cast<const float4*>(xb + ((g0 + 8) ^ rm) * 16);
        float4 xc1 = *reinterpret_cast<const float4*>(xb + ((g0 + 9) ^ rm) * 16);

        // issue ALL B loads for this step BEFORE the next HBM prefetch:
        // their use-waits then never drain the slow DMA (in-order retirement)
        const int ksl0 = st * 8 + (lane >> 4);
        const unsigned short* bp0 = wBbase + ((size_t)ksl0 * 64 + (lane & 15)) * 8;
        const unsigned short* bp1 = bp0 + 4 * 64 * 8;   // +4 kslots
        short8 b0h[4], b0l[4], b1h[4], b1l[4];
        #pragma unroll
        for (int n = 0; n < 4; ++n) {
            b0h[n] = *reinterpret_cast<const short8*>(bp0 + n * 128);
            b0l[n] = *reinterpret_cast<const short8*>(bp0 + WSPLIT_SHORTS + n * 128);
            b1h[n] = *reinterpret_cast<const short8*>(bp1 + n * 128);
            b1l[n] = *reinterpret_cast<const short8*>(bp1 + WSPLIT_SHORTS + n * 128);
        }
        __builtin_amdgcn_sched_barrier(0);   // pin: B issued before DMA below

        if (st + 1 < NSTEP) STAGE(st + 1, (st + 1) & 1);
        __builtin_amdgcn_sched_barrier(0);   // pin: DMA issued before compute

        // ---- compute phase 0 ----
        short8 ah, al;
        split8(xa0, xc0, ah, al);
        #pragma unroll
        for (int n = 0; n < 4; ++n)
            acc[n] = __builtin_amdgcn_mfma_f32_16x16x32_bf16(ah, b0h[n], acc[n], 0, 0, 0);
        #pragma unroll
        for (int n = 0; n < 4; ++n)
            acc[n] = __builtin_amdgcn_mfma_f32_16x16x32_bf16(ah, b0l[n], acc[n], 0, 0, 0);
        #pragma unroll
        for (int n = 0; n < 4; ++n)
            acc[n] = __builtin_amdgcn_mfma_f32_16x16x32_bf16(al, b0h[n], acc[n], 0, 0, 0);

        // ---- compute phase 1 ----
        split8(xa1, xc1, ah, al);
        #pragma unroll
        for (int n = 0; n < 4; ++n)
            acc[n] = __builtin_amdgcn_mfma_f32_16x16x32_bf16(ah, b1h[n], acc[n], 0, 0, 0);
        #pragma unroll
        for (int n = 0; n < 4; ++n)
            acc[n] = __builtin_amdgcn_mfma_f32_16x16x32_bf16(ah, b1l[n], acc[n], 0, 0, 0);
        #pragma unroll
        for (int n = 0; n < 4; ++n)
            acc[n] = __builtin_amdgcn_mfma_f32_16x16x32_bf16(al, b1h[n], acc[n], 0, 0, 0);
    }

    __syncthreads();   // first block-wide sync: before LDS reuse

    // ---- 4-way k-reduce via LDS ----
    float* const part = reinterpret_cast<float*>(smem);            // 3072 f32
    float* const Lb   = reinterpret_cast<float*>(smem + 12288);    // [64 e][17]
    float* const red  = reinterpret_cast<float*>(smem + 17792);    // 512 f32

    if (ksw > 0) {
        #pragma unroll
        for (int n = 0; n < 4; ++n)
            #pragma unroll
            for (int j = 0; j < 4; ++j)
                part[(ksw - 1) * 1024 + lane * 16 + n * 4 + j] = acc[n][j];
    }
    __syncthreads();
    if (ksw == 0) {
        #pragma unroll
        for (int n = 0; n < 4; ++n) {
            #pragma unroll
            for (int j = 0; j < 4; ++j) {
                float v = acc[n][j]
                        + part[0 * 1024 + lane * 16 + n * 4 + j]
                        + part[1 * 1024 + lane * 16 + n * 4 + j]
                        + part[2 * 1024 + lane * 16 + n * 4 + j];
                // C layout (m89-verified): col = lane&15, row = (lane>>4)*4 + j
                const int e  = n * 16 + (lane & 15);
                const int rl = (lane >> 4) * 4 + j;
                Lb[e * 17 + rl] = v;
            }
        }
    }
    __syncthreads();

    // ---- softmax + top-2 per row (lane = expert), 4 rows/wave ----
    float impAcc = 0.f, cntAcc = 0.f;
    const float blane = b[lane];
    float* outIdx = out;
    float* outVal = out + (size_t)SROWS * 2;

    #pragma unroll 1
    for (int rr = 0; rr < 4; ++rr) {
        const int r = ksw * 4 + rr;
        const float logit = Lb[lane * 17 + r] + blane;

        float v1 = logit; int i1 = lane;
        #pragma unroll
        for (int off = 32; off; off >>= 1) {
            float ov = __shfl_xor(v1, off);
            int   oi = __shfl_xor(i1, off);
            if (ov > v1 || (ov == v1 && oi < i1)) { v1 = ov; i1 = oi; }
        }
        float p = expf(logit - v1);
        float ssum = p;
        #pragma unroll
        for (int off = 32; off; off >>= 1) ssum += __shfl_xor(ssum, off);

        float v2 = (lane == i1) ? -3.402823466e38f : logit;
        int i2 = lane;
        #pragma unroll
        for (int off = 32; off; off >>= 1) {
            float ov = __shfl_xor(v2, off);
            int   oi = __shfl_xor(i2, off);
            if (ov > v2 || (ov == v2 && oi < i2)) { v2 = ov; i2 = oi; }
        }

        impAcc += p / ssum;
        cntAcc += (i1 == lane) ? 1.f : 0.f;

        if (lane == 0) {
            const int sr = row0 + r;
            outIdx[sr * 2 + 0] = (float)i1;
            outIdx[sr * 2 + 1] = (float)i2;
            outVal[sr * 2 + 0] = 1.f / ssum;
            outVal[sr * 2 + 1] = expf(v2 - v1) / ssum;
        }
    }

    // ---- per-block reduce of importance / count partials ----
    __syncthreads();
    red[ksw * 64 + lane]       = impAcc;
    red[256 + ksw * 64 + lane] = cntAcc;
    __syncthreads();
    if (tid < 64) {
        float si = 0.f, sc2 = 0.f;
        #pragma unroll
        for (int g = 0; g < 4; ++g) {
            si  += red[g * 64 + tid];
            sc2 += red[256 + g * 64 + tid];
        }
        ws[WSOFF_F + (size_t)blockIdx.x * 64 + tid] = si;
        ws[WSOFF2  + (size_t)blockIdx.x * 64 + tid] = sc2;
    }
}

__global__ void gate_reduce(const float* __restrict__ ws, float* __restrict__ out)
{
    __shared__ float li[64 * 64], lc[64 * 64];     // [group][expert]
    const int t = threadIdx.x;                     // 1024 threads
    const int g  = t >> 4;                         // 0..63, 16 blocks each
    const int e4 = (t & 15) * 4;                   // expert quad
    float4 si = make_float4(0.f, 0.f, 0.f, 0.f);
    float4 sc = make_float4(0.f, 0.f, 0.f, 0.f);
    const int base = g * 16;
    #pragma unroll 4
    for (int bb = base; bb < base + 16; ++bb) {
        float4 a = *reinterpret_cast<const float4*>(&ws[WSOFF_F + (size_t)bb * 64 + e4]);
        float4 c = *reinterpret_cast<const float4*>(&ws[WSOFF2  + (size_t)bb * 64 + e4]);
        si.x += a.x; si.y += a.y; si.z += a.z; si.w += a.w;
        sc.x += c.x; sc.y += c.y; sc.z += c.z; sc.w += c.w;
    }
    *reinterpret_cast<float4*>(&li[g * 64 + e4]) = si;
    *reinterpret_cast<float4*>(&lc[g * 64 + e4]) = sc;
    __syncthreads();
    if (t < 64) {
        float ti = 0.f, tc = 0.f;
        #pragma unroll 8
        for (int gg = 0; gg < 64; ++gg) { ti += li[gg * 64 + t]; tc += lc[gg * 64 + t]; }
        li[t] = ti * tc;    // reuse row 0
    }
    __syncthreads();
    if (t == 0) {
        float s = 0.f;
        for (int i = 0; i < NE; ++i) s += li[i];
        out[(size_t)SROWS * 4] = s * ((float)NE / ((float)SROWS * (float)SROWS));
    }
}

extern "C" void kernel_launch(void* const* d_in, const int* in_sizes, int n_in,
                              void* d_out, int out_size, void* d_ws, size_t ws_size,
                              hipStream_t stream)
{
    const float* x = (const float*)d_in[0];
    const float* W = (const float*)d_in[1];
    const float* b = (const float*)d_in[2];
    float* out = (float*)d_out;
    unsigned short* wsp = (unsigned short*)d_ws;
    float* wsf = (float*)d_ws;

    w_split<<<128, 256, 0, stream>>>(W, wsp);
    gate_main<<<NBLK, 256, 0, stream>>>(x, wsp, b, out, wsf);
    gate_reduce<<<1, 1024, 0, stream>>>(wsf, out);
}

// Round 13
// 82.017 us; speedup vs baseline: 1.1570x; 1.0373x over previous
//
#include <hip/hip_runtime.h>
#include <hip/hip_bf16.h>

#define SROWS 16384
#define DIMK  4096
#define NE    64
#define BM    64                // rows per block (4 M-tiles)
#define NBLK  (SROWS/BM)        // 256 blocks = 1/CU
#define NSTEP 16                // per step each ksw-wave consumes 64 k
#define WSPLIT_SHORTS 262144    // shorts per (hi|lo) plane of pre-split W
#define WSOFF_F 262144          // f32 offset of partials region (skip 1 MB W-split)
#define WSOFF2  (WSOFF_F + NBLK*64)
#define LDS_BYTES 131072        // 2 x 64 KB B double buffer

typedef __attribute__((ext_vector_type(8))) short short8;
typedef __attribute__((ext_vector_type(4))) float f32x4;

// split 8 f32 -> 8 hi bf16 + 8 lo bf16 via HW cvt (RNE); f ~= hi + lo
__device__ __forceinline__ void split8(const float4 a, const float4 c, short8& hi, short8& lo) {
    float f[8] = {a.x, a.y, a.z, a.w, c.x, c.y, c.z, c.w};
    #pragma unroll
    for (int i = 0; i < 8; ++i) {
        unsigned short h = __bfloat16_as_ushort(__float2bfloat16(f[i]));
        float hf = __uint_as_float((unsigned)h << 16);
        unsigned short l = __bfloat16_as_ushort(__float2bfloat16(f[i] - hf));
        hi[i] = (short)h;
        lo[i] = (short)l;
    }
}

// pre-pass: split W into bf16 hi/lo planes in B-fragment order [k/8][e][8]
__global__ void w_split(const float* __restrict__ W, unsigned short* __restrict__ wsp)
{
    const int idx   = blockIdx.x * 256 + threadIdx.x;   // 0..32767
    const int kslot = idx & 511;
    const int e     = idx >> 9;
    const float* p = W + (size_t)e * DIMK + kslot * 8;
    float4 va = *reinterpret_cast<const float4*>(p);
    float4 vb = *reinterpret_cast<const float4*>(p + 4);
    short8 hi, lo;
    split8(va, vb, hi, lo);
    *reinterpret_cast<short8*>(wsp + (size_t)(kslot * 64 + e) * 8)                 = hi;
    *reinterpret_cast<short8*>(wsp + WSPLIT_SHORTS + (size_t)(kslot * 64 + e) * 8) = lo;
}

// async global -> LDS, 16B per lane (DMA; dst = wave-uniform base + lane*16)
__device__ __forceinline__ void gl_lds16(const void* g, void* l) {
    __builtin_amdgcn_global_load_lds(
        (const __attribute__((address_space(1))) void*)g,
        (__attribute__((address_space(3))) void*)l, 16, 0, 0);
}

__global__ __launch_bounds__(1024, 4) void gate_main(
    const float* __restrict__ x, const unsigned short* __restrict__ wsp,
    const float* __restrict__ b, float* __restrict__ out, float* __restrict__ ws)
{
    extern __shared__ __align__(16) char smem[];
    // main loop: B double buffer, buf s at smem + s*65536:
    //   within buf: [ksw(4)][plane(2)][kslot(8)][granule e-major: (n*16+e16)*16B]
    // epilogue alias: part[12*1024 f32] | Lb[64*65 f32] @49152 | red[2048 f32] @66048

    const int tid  = threadIdx.x;
    const int lane = tid & 63;
    const int wid  = __builtin_amdgcn_readfirstlane(tid >> 6);  // 0..15
    const int mw   = wid & 3;      // M-tile (16 rows)
    const int ksw  = wid >> 2;     // k-split quarter (1024 k)
    const int row0 = blockIdx.x * BM;

    // ---- B staging: 4 DMA instrs/step, instr j loads ksw=j's 16 KB ----
    const int spl = tid >> 9;            // plane 0/1
    const int skl = (tid >> 6) & 7;      // kslot within step
    const int se  = tid & 63;            // expert
    const unsigned short* bsrc[4];
    #pragma unroll
    for (int j = 0; j < 4; ++j)
        bsrc[j] = wsp + (size_t)spl * WSPLIT_SHORTS
                + ((size_t)((j * 128 + skl) * 64 + se)) * 8;

    auto STAGE_B = [&](int st, int bsel) {
        char* Bb = smem + bsel * 65536;
        #pragma unroll
        for (int j = 0; j < 4; ++j)
            gl_lds16(bsrc[j] + (size_t)st * 4096, Bb + j * 16384 + tid * 16);
    };

    // ---- x: per-lane private fragment stream, direct to regs ----
    const float* xA = x + (size_t)(row0 + mw * 16 + (lane & 15)) * DIMK
                        + ksw * 1024 + (lane >> 4) * 8;

    f32x4 acc[4];
    #pragma unroll
    for (int n = 0; n < 4; ++n) acc[n] = (f32x4){0.f, 0.f, 0.f, 0.f};

    // prologue
    float4 a00 = *reinterpret_cast<const float4*>(xA);
    float4 a01 = *reinterpret_cast<const float4*>(xA + 4);
    float4 a10 = *reinterpret_cast<const float4*>(xA + 32);
    float4 a11 = *reinterpret_cast<const float4*>(xA + 36);
    STAGE_B(0, 0);
    asm volatile("s_waitcnt vmcnt(0)" ::: "memory");
    __builtin_amdgcn_s_barrier();
    __builtin_amdgcn_sched_barrier(0);

    const int kb0 = (lane >> 4) * 1024 + (lane & 15) * 16;  // phase-0 frag base in ksw slab

    #pragma unroll 1
    for (int st = 0; st < NSTEP; ++st) {
        float4 p00, p01, p10, p11;
        const bool hn = (st + 1 < NSTEP);
        if (hn) {
            const float* xp = xA + (size_t)(st + 1) * 64;
            p00 = *reinterpret_cast<const float4*>(xp);
            p01 = *reinterpret_cast<const float4*>(xp + 4);
            p10 = *reinterpret_cast<const float4*>(xp + 32);
            p11 = *reinterpret_cast<const float4*>(xp + 36);
            STAGE_B(st + 1, (st + 1) & 1);
        }
        __builtin_amdgcn_sched_barrier(0);   // prefetch issued before compute

        const char* Bb = smem + (st & 1) * 65536 + ksw * 16384 + kb0;

        // ---- phase 0 (k window [st*64, +32)) ----
        short8 ah, al;
        split8(a00, a01, ah, al);
        #pragma unroll
        for (int n = 0; n < 4; ++n) {
            short8 bh = *reinterpret_cast<const short8*>(Bb + n * 256);
            short8 bl = *reinterpret_cast<const short8*>(Bb + 8192 + n * 256);
            acc[n] = __builtin_amdgcn_mfma_f32_16x16x32_bf16(ah, bh, acc[n], 0, 0, 0);
            acc[n] = __builtin_amdgcn_mfma_f32_16x16x32_bf16(ah, bl, acc[n], 0, 0, 0);
            acc[n] = __builtin_amdgcn_mfma_f32_16x16x32_bf16(al, bh, acc[n], 0, 0, 0);
        }

        // ---- phase 1 (k window [st*64+32, +32); kslot +4 -> +4096 B) ----
        split8(a10, a11, ah, al);
        #pragma unroll
        for (int n = 0; n < 4; ++n) {
            short8 bh = *reinterpret_cast<const short8*>(Bb + 4096 + n * 256);
            short8 bl = *reinterpret_cast<const short8*>(Bb + 4096 + 8192 + n * 256);
            acc[n] = __builtin_amdgcn_mfma_f32_16x16x32_bf16(ah, bh, acc[n], 0, 0, 0);
            acc[n] = __builtin_amdgcn_mfma_f32_16x16x32_bf16(ah, bl, acc[n], 0, 0, 0);
            acc[n] = __builtin_amdgcn_mfma_f32_16x16x32_bf16(al, bh, acc[n], 0, 0, 0);
        }

        // step end: drain next-step loads (had the whole compute phase), sync buffers
        asm volatile("s_waitcnt vmcnt(0)" ::: "memory");
        __builtin_amdgcn_s_barrier();
        __builtin_amdgcn_sched_barrier(0);
        if (hn) { a00 = p00; a01 = p01; a10 = p10; a11 = p11; }
    }

    __syncthreads();

    // ---- 4-way k-reduce via LDS ----
    float* const part = reinterpret_cast<float*>(smem);            // 12*1024 f32
    float* const Lb   = reinterpret_cast<float*>(smem + 49152);    // [64 e][65]
    float* const red  = reinterpret_cast<float*>(smem + 66048);    // 2*1024 f32

    if (ksw > 0) {
        const int base = ((ksw - 1) * 4 + mw) * 1024 + lane * 16;
        #pragma unroll
        for (int n = 0; n < 4; ++n)
            #pragma unroll
            for (int j = 0; j < 4; ++j)
                part[base + n * 4 + j] = acc[n][j];
    }
    __syncthreads();
    if (ksw == 0) {
        #pragma unroll
        for (int n = 0; n < 4; ++n) {
            #pragma unroll
            for (int j = 0; j < 4; ++j) {
                float v = acc[n][j]
                        + part[(0 * 4 + mw) * 1024 + lane * 16 + n * 4 + j]
                        + part[(1 * 4 + mw) * 1024 + lane * 16 + n * 4 + j]
                        + part[(2 * 4 + mw) * 1024 + lane * 16 + n * 4 + j];
                // C layout (m89-verified): col = lane&15, row = (lane>>4)*4 + j
                const int e  = n * 16 + (lane & 15);
                const int rl = mw * 16 + (lane >> 4) * 4 + j;
                Lb[e * 65 + rl] = v;
            }
        }
    }
    __syncthreads();

    // ---- softmax + top-2 per row (lane = expert), 4 rows/wave ----
    float impAcc = 0.f, cntAcc = 0.f;
    const float blane = b[lane];
    float* outIdx = out;
    float* outVal = out + (size_t)SROWS * 2;

    #pragma unroll 1
    for (int rr = 0; rr < 4; ++rr) {
        const int r = wid * 4 + rr;
        const float logit = Lb[lane * 65 + r] + blane;

        float v1 = logit; int i1 = lane;
        #pragma unroll
        for (int off = 32; off; off >>= 1) {
            float ov = __shfl_xor(v1, off);
            int   oi = __shfl_xor(i1, off);
            if (ov > v1 || (ov == v1 && oi < i1)) { v1 = ov; i1 = oi; }
        }
        float p = expf(logit - v1);
        float ssum = p;
        #pragma unroll
        for (int off = 32; off; off >>= 1) ssum += __shfl_xor(ssum, off);

        float v2 = (lane == i1) ? -3.402823466e38f : logit;
        int i2 = lane;
        #pragma unroll
        for (int off = 32; off; off >>= 1) {
            float ov = __shfl_xor(v2, off);
            int   oi = __shfl_xor(i2, off);
            if (ov > v2 || (ov == v2 && oi < i2)) { v2 = ov; i2 = oi; }
        }

        impAcc += p / ssum;
        cntAcc += (i1 == lane) ? 1.f : 0.f;

        if (lane == 0) {
            const int sr = row0 + r;
            outIdx[sr * 2 + 0] = (float)i1;
            outIdx[sr * 2 + 1] = (float)i2;
            outVal[sr * 2 + 0] = 1.f / ssum;
            outVal[sr * 2 + 1] = expf(v2 - v1) / ssum;
        }
    }

    // ---- per-block reduce of importance / count partials ----
    __syncthreads();
    red[wid * 64 + lane]        = impAcc;
    red[1024 + wid * 64 + lane] = cntAcc;
    __syncthreads();
    if (tid < 64) {
        float si = 0.f, sc2 = 0.f;
        #pragma unroll
        for (int g = 0; g < 16; ++g) {
            si  += red[g * 64 + tid];
            sc2 += red[1024 + g * 64 + tid];
        }
        ws[WSOFF_F + (size_t)blockIdx.x * 64 + tid] = si;
        ws[WSOFF2  + (size_t)blockIdx.x * 64 + tid] = sc2;
    }
}

__global__ void gate_reduce(const float* __restrict__ ws, float* __restrict__ out)
{
    __shared__ float li[64 * 64], lc[64 * 64];     // [group][expert]
    const int t = threadIdx.x;                     // 1024 threads
    const int g  = t >> 4;                         // 0..63, 4 blocks each
    const int e4 = (t & 15) * 4;                   // expert quad
    float4 si = make_float4(0.f, 0.f, 0.f, 0.f);
    float4 sc = make_float4(0.f, 0.f, 0.f, 0.f);
    const int base = g * 4;
    #pragma unroll
    for (int bb = base; bb < base + 4; ++bb) {
        float4 a = *reinterpret_cast<const float4*>(&ws[WSOFF_F + (size_t)bb * 64 + e4]);
        float4 c = *reinterpret_cast<const float4*>(&ws[WSOFF2  + (size_t)bb * 64 + e4]);
        si.x += a.x; si.y += a.y; si.z += a.z; si.w += a.w;
        sc.x += c.x; sc.y += c.y; sc.z += c.z; sc.w += c.w;
    }
    *reinterpret_cast<float4*>(&li[g * 64 + e4]) = si;
    *reinterpret_cast<float4*>(&lc[g * 64 + e4]) = sc;
    __syncthreads();
    if (t < 64) {
        float ti = 0.f, tc = 0.f;
        #pragma unroll 8
        for (int gg = 0; gg < 64; ++gg) { ti += li[gg * 64 + t]; tc += lc[gg * 64 + t]; }
        li[t] = ti * tc;    // reuse row 0
    }
    __syncthreads();
    if (t == 0) {
        float s = 0.f;
        for (int i = 0; i < NE; ++i) s += li[i];
        out[(size_t)SROWS * 4] = s * ((float)NE / ((float)SROWS * (float)SROWS));
    }
}

extern "C" void kernel_launch(void* const* d_in, const int* in_sizes, int n_in,
                              void* d_out, int out_size, void* d_ws, size_t ws_size,
                              hipStream_t stream)
{
    const float* x = (const float*)d_in[0];
    const float* W = (const float*)d_in[1];
    const float* b = (const float*)d_in[2];
    float* out = (float*)d_out;
    unsigned short* wsp = (unsigned short*)d_ws;
    float* wsf = (float*)d_ws;

    hipFuncSetAttribute(reinterpret_cast<const void*>(gate_main),
                        hipFuncAttributeMaxDynamicSharedMemorySize, LDS_BYTES);

    w_split<<<128, 256, 0, stream>>>(W, wsp);
    gate_main<<<NBLK, 1024, LDS_BYTES, stream>>>(x, wsp, b, out, wsf);
    gate_reduce<<<1, 1024, 0, stream>>>(wsf, out);
}